// Round 6
// baseline (324.822 us; speedup 1.0000x reference)
//
#include <hip/hip_runtime.h>
#include <stdint.h>

typedef unsigned short u16;
typedef __attribute__((ext_vector_type(8))) short short8;
typedef __attribute__((ext_vector_type(4))) float floatx4;

#define S_LEN 2048
#define NQKV 3072

#if __has_builtin(__builtin_amdgcn_exp2f)
#define EXP2F __builtin_amdgcn_exp2f
#else
#define EXP2F exp2f
#endif

__device__ inline float bf2f(u16 u) {
  union { uint32_t u; float f; } v; v.u = ((uint32_t)u) << 16; return v.f;
}
__device__ inline u16 f2bf(float f) {
  union { float f; uint32_t u; } v; v.f = f;
  uint32_t r = v.u + 0x7fffu + ((v.u >> 16) & 1u);
  return (u16)(r >> 16);
}
__device__ inline void gl2lds16(const u16* g, u16* l) {
  __builtin_amdgcn_global_load_lds((const __attribute__((address_space(1))) uint32_t*)g,
                                   (__attribute__((address_space(3))) uint32_t*)l, 16, 0, 0);
}

// ---------------- cast fp32 -> bf16, 4 elems/thread ----------------
__global__ void cast_k(const float* __restrict__ in, u16* __restrict__ out, int n4) {
  int i = blockIdx.x * 256 + threadIdx.x;
  if (i >= n4) return;
  float4 v = ((const float4*)in)[i];
  ushort4 o;
  o.x = f2bf(v.x); o.y = f2bf(v.y); o.z = f2bf(v.z); o.w = f2bf(v.w);
  ((ushort4*)out)[i] = o;
}

// ---------------- fused weight transpose+cast: 4 weights in ONE launch ----------------
__global__ void wtrans_k(const float* __restrict__ Wq, const float* __restrict__ Wk,
                         const float* __restrict__ Wv, const float* __restrict__ Wo,
                         u16* __restrict__ WT, u16* __restrict__ WoT) {
  __shared__ u16 tile[32][33];
  const int z = blockIdx.z;
  const float* src; u16* dst; int N;
  if (z == 0)      { src = Wq; dst = WT;                       N = 2048; }
  else if (z == 1) { src = Wk; dst = WT + (size_t)2048 * 2048; N = 512;  }
  else if (z == 2) { src = Wv; dst = WT + (size_t)2560 * 2048; N = 512;  }
  else             { src = Wo; dst = WoT;                      N = 2048; }
  int n0 = blockIdx.x * 32, k0 = blockIdx.y * 32;
  if (n0 >= N) return;
  int tx = threadIdx.x, ty = threadIdx.y;  // 32 x 8
#pragma unroll
  for (int i = 0; i < 4; i++)
    tile[ty + 8 * i][tx] = f2bf(src[(size_t)(k0 + ty + 8 * i) * N + n0 + tx]);
  __syncthreads();
#pragma unroll
  for (int i = 0; i < 4; i++)
    dst[(size_t)(n0 + ty + 8 * i) * 2048 + k0 + tx] = tile[tx][ty + 8 * i];
}

// ---------------- V transpose: qkv V region [key][d] -> vt [bz][d][key] (bf16) ----------------
__global__ void vtrans_k(const u16* __restrict__ qkv, u16* __restrict__ vt) {
  __shared__ u16 tile[32][33];
  int bk = blockIdx.x * 32, bd = blockIdx.y * 32, bz = blockIdx.z;
  int bb = bz >> 2, kvh = bz & 3;
  const u16* src = qkv + ((size_t)bb * S_LEN) * NQKV + 2560 + kvh * 128;
  u16* dst = vt + (size_t)bz * 128 * 2048;
  int tx = threadIdx.x, ty = threadIdx.y;
#pragma unroll
  for (int i = 0; i < 4; i++)
    tile[ty + 8 * i][tx] = src[(size_t)(bk + ty + 8 * i) * NQKV + bd + tx];
  __syncthreads();
#pragma unroll
  for (int i = 0; i < 4; i++)
    dst[(size_t)(bd + ty + 8 * i) * 2048 + bk + tx] = tile[tx][ty + 8 * i];
}

// ---------------- GEMM (legacy 128x128, used for Wo projection) ----------------
template <bool OUTF32>
__global__ __launch_bounds__(256) void gemm_bt(const u16* __restrict__ A, const u16* __restrict__ Bt,
                                               void* __restrict__ Cv, int M, int N, int K) {
  __shared__ u16 As[128 * 32];
  __shared__ u16 Bs[128 * 32];
  const int m0 = blockIdx.y * 128, n0 = blockIdx.x * 128;
  const int t = threadIdx.x, w = t >> 6, lane = t & 63;
  const int quad = lane >> 4, l16 = lane & 15;
  const int wm = (w >> 1) * 64, wn = (w & 1) * 64;
  const int lrow = lane >> 2, lk = (lane & 3) * 8;
  floatx4 acc[4][4] = {};
  for (int k0 = 0; k0 < K; k0 += 32) {
#pragma unroll
    for (int c = 2 * w; c <= 2 * w + 1; ++c) {
      int row = c * 16 + lrow;
      gl2lds16(A + (size_t)(m0 + row) * K + k0 + lk, As + c * 512 + lane * 8);
      gl2lds16(Bt + (size_t)(n0 + row) * K + k0 + lk, Bs + c * 512 + lane * 8);
    }
    __syncthreads();
    short8 a[4], b[4];
#pragma unroll
    for (int mt = 0; mt < 4; mt++) a[mt] = *(const short8*)(As + (wm + mt * 16 + l16) * 32 + quad * 8);
#pragma unroll
    for (int nt = 0; nt < 4; nt++) b[nt] = *(const short8*)(Bs + (wn + nt * 16 + l16) * 32 + quad * 8);
#pragma unroll
    for (int mt = 0; mt < 4; mt++)
#pragma unroll
      for (int nt = 0; nt < 4; nt++)
        acc[mt][nt] = __builtin_amdgcn_mfma_f32_16x16x32_bf16(a[mt], b[nt], acc[mt][nt], 0, 0, 0);
    __syncthreads();
  }
#pragma unroll
  for (int mt = 0; mt < 4; mt++)
#pragma unroll
    for (int nt = 0; nt < 4; nt++)
#pragma unroll
      for (int r = 0; r < 4; r++) {
        int row = m0 + wm + mt * 16 + quad * 4 + r;
        int col = n0 + wn + nt * 16 + l16;
        if (OUTF32)
          ((float*)Cv)[(size_t)row * N + col] = acc[mt][nt][r];
        else
          ((u16*)Cv)[(size_t)row * N + col] = f2bf(acc[mt][nt][r]);
      }
}

// ---------------- GEMM 256x256 8-phase (REVERTED to R4 structure) ----------------
// R5's read-ahead bunching regressed (83.5us, MfmaUtil 23): bursty LDS demand
// in lockstep. This is the verified R4 version (66.6us): fragment reuse across
// quadrant phases, reads evenly spread, lgkmcnt(0)+counted vmcnt, XOR swizzle.
__global__ __launch_bounds__(512, 2) void gemm256_k(const u16* __restrict__ A,
                                                    const u16* __restrict__ Bt,
                                                    u16* __restrict__ C, int N, int K) {
  __shared__ u16 Al[2][2][8192];
  __shared__ u16 Bl[2][2][8192];
  const int TN = N >> 8;
  int flat = blockIdx.x;
  const int cpx = gridDim.x >> 3;  // grid % 8 == 0 guaranteed by launch config
  flat = (flat & 7) * cpx + (flat >> 3);
  const int m0 = (flat / TN) << 8, n0 = (flat % TN) << 8;
  const int t = threadIdx.x, w = t >> 6, lane = t & 63;
  const int quad = lane >> 4, l16 = lane & 15;
  const int wm = w >> 2, wn = w & 3;
  const int sr = t >> 3, sl = t & 7;  // staging: row-in-round, lds slot
  floatx4 acc[2][2][4][2] = {};
  const int NKT = K >> 6;

  const int ra_l = wm * 64 + l16;  // + mt*16 ; A row within 128-half
  const int rb_l = wn * 32 + l16;  // + nt*16 ; B row within 128-half

  // prologue: stage kt0 into buf0 (A0,B0,B1,A1), full drain once
#pragma unroll
  for (int round = 0; round < 2; round++) {
    int r = round * 64 + sr;
    int so = (sl ^ (r & 7)) << 3;
    gl2lds16(A + (size_t)(m0 + r) * K + so, &Al[0][0][0] + round * 4096 + t * 8);
    gl2lds16(Bt + (size_t)(n0 + r) * K + so, &Bl[0][0][0] + round * 4096 + t * 8);
    gl2lds16(Bt + (size_t)(n0 + 128 + r) * K + so, &Bl[0][1][0] + round * 4096 + t * 8);
    gl2lds16(A + (size_t)(m0 + 128 + r) * K + so, &Al[0][1][0] + round * 4096 + t * 8);
  }
  asm volatile("s_waitcnt vmcnt(0)" ::: "memory");
  __builtin_amdgcn_s_barrier();

  short8 af[4][2];     // current A-half fragments (reused by 2 phases)
  short8 bf[2][2][2];  // [nh][nt][ks] both B-half fragments

  for (int kt = 0; kt < NKT; kt++) {
    const int c = kt & 1;
    const u16* Ab = &Al[c][0][0];
    const u16* Bb = &Bl[c][0][0];
    u16* An = &Al[c ^ 1][0][0];
    u16* Bn = &Bl[c ^ 1][0][0];
    const int k1 = (kt + 1) << 6;
    const bool pf = (kt + 1 < NKT);
#pragma unroll
    for (int ph = 0; ph < 4; ph++) {
      // quadrant sequence: (mh,nh) = (0,0),(0,1),(1,1),(1,0)
      const int mh = (ph >> 1);
      const int nh = (ph == 1 || ph == 2) ? 1 : 0;
      // ---- ds-read ONLY the new fragments for this phase ----
      if (ph == 0 || ph == 2) {  // new A-half
#pragma unroll
        for (int mt = 0; mt < 4; mt++) {
          int ra = ra_l + mt * 16;
          const u16* base = Ab + mh * 8192 + ra * 64;
#pragma unroll
          for (int ks = 0; ks < 2; ks++)
            af[mt][ks] = *(const short8*)(base + (((ks * 4 + quad) ^ (ra & 7)) << 3));
        }
      }
      if (ph == 0 || ph == 1) {  // new B-half
#pragma unroll
        for (int nt = 0; nt < 2; nt++) {
          int rb = rb_l + nt * 16;
          const u16* base = Bb + nh * 8192 + rb * 64;
#pragma unroll
          for (int ks = 0; ks < 2; ks++)
            bf[nh][nt][ks] = *(const short8*)(base + (((ks * 4 + quad) ^ (rb & 7)) << 3));
        }
      }
      // ---- stage one half-tile of kt+1 (order A0,B0,B1,A1) ----
      if (pf) {
        const u16* G;
        u16* L;
        int rbase;
        if (ph == 0)      { G = A;  L = An;        rbase = m0; }
        else if (ph == 1) { G = Bt; L = Bn;        rbase = n0; }
        else if (ph == 2) { G = Bt; L = Bn + 8192; rbase = n0 + 128; }
        else              { G = A;  L = An + 8192; rbase = m0 + 128; }
#pragma unroll
        for (int round = 0; round < 2; round++) {
          int r = round * 64 + sr;
          gl2lds16(G + (size_t)(rbase + r) * K + k1 + ((sl ^ (r & 7)) << 3),
                   L + round * 4096 + t * 8);
        }
      }
      __builtin_amdgcn_s_barrier();
      asm volatile("s_waitcnt lgkmcnt(0)" ::: "memory");
      __builtin_amdgcn_s_setprio(1);
#pragma unroll
      for (int mt = 0; mt < 4; mt++)
#pragma unroll
        for (int nt = 0; nt < 2; nt++)
#pragma unroll
          for (int ks = 0; ks < 2; ks++)
            acc[mh][nh][mt][nt] =
                __builtin_amdgcn_mfma_f32_16x16x32_bf16(af[mt][ks], bf[nh][nt][ks], acc[mh][nh][mt][nt], 0, 0, 0);
      __builtin_amdgcn_s_setprio(0);
      if (ph != 2) asm volatile("s_waitcnt vmcnt(4)" ::: "memory");
      __builtin_amdgcn_s_barrier();
    }
  }
  // ---- epilogue ----
#pragma unroll
  for (int mh = 0; mh < 2; mh++)
#pragma unroll
    for (int nh = 0; nh < 2; nh++)
#pragma unroll
      for (int mt = 0; mt < 4; mt++)
#pragma unroll
        for (int nt = 0; nt < 2; nt++)
#pragma unroll
          for (int r = 0; r < 4; r++) {
            int row = m0 + mh * 128 + wm * 64 + mt * 16 + quad * 4 + r;
            int col = n0 + nh * 128 + wn * 32 + nt * 16 + l16;
            C[(size_t)row * N + col] = f2bf(acc[mh][nh][mt][nt][r]);
          }
}

// ---------------- RoPE in place on QKV buffer (bf16), Q + K heads only ----------------
__global__ void rope_k(u16* __restrict__ qkv, const int* __restrict__ pos) {
  int idx = blockIdx.x * 256 + threadIdx.x;
  int i = idx & 63;
  int hh = (idx >> 6) % 20;
  int row = idx / (64 * 20);
  int s = row & (S_LEN - 1);
  float p = (float)pos[s];
  float freq = __expf(-(float)i * 0.015625f * 9.210340371976184f);
  float ang = p * freq;
  float c = cosf(ang), sn = sinf(ang);
  int col = (hh < 16) ? hh * 128 : 2048 + (hh - 16) * 128;
  size_t base = (size_t)row * NQKV + col + i;
  float t1 = bf2f(qkv[base]), t2 = bf2f(qkv[base + 64]);
  qkv[base] = f2bf(t1 * c - t2 * sn);
  qkv[base + 64] = f2bf(t2 * c + t1 * sn);
}

// ---------------- Flash attention, causal GQA (R6: 32 q-rows/wave) ----------------
// R4 budget per-SIMD: LDS reads 27.5us (dominant), MFMA 18us, VALU 6us. All 4
// waves read IDENTICAL K/V fragments from LDS (fragment addr is wave-independent)
// -> 4x redundancy at 16 q/wave. R6: 32 q-rows/wave: each K/V fragment read
// feeds TWO Q-fragments' MFMAs -> LDS read time per output halves (~14us).
// Block = 4 waves x 32 q = 128-row q-tiles; 16 tiles; pair-balanced grid
// (8,16,2) = 256 blocks = 1/CU. Wave-uniform skip: waves 0,1 skip the tile's
// last 64-key block (fully masked for their rows) but keep barriers+DMA.
// Same 64-key block order and per-q accumulation order -> bit-identical to R4.
__global__ __launch_bounds__(256) void attn_k(const u16* __restrict__ qkv,
                                              const u16* __restrict__ vt,
                                              u16* __restrict__ ctx) {
  __shared__ u16 Kl[2][64 * 128];      // 2 x 16384 B, [pos][d] swizzled, rows kperm'd
  __shared__ u16 Vl[2][128 * 64];      // 2 x 16384 B, [d][key] swizzled
  const int p = blockIdx.x;            // 0..7
  const int h = blockIdx.y, bb = blockIdx.z;
  const int kvh = h >> 2;
  const int t = threadIdx.x, w = t >> 6, lane = t & 63;
  const int quad = lane >> 4, l16 = lane & 15;
  const int sx = l16 & 7;              // read-side swizzle key
  const int kslot = lane & 15;
  const int vd0 = w * 32 + (lane >> 3);
  const int vslot = lane & 7;
  const int grow0 = (w & 1) * 4 + (w >> 1) * 32 + quad;  // kperm staging base
  const size_t rowbase = (size_t)bb * S_LEN;
  const u16* Kg0 = qkv + rowbase * NQKV + 2048 + kvh * 128;
  const u16* Vg0 = vt + (size_t)(bb * 4 + kvh) * 128 * 2048;
  const float c2 = 0.12751744f;  // (1/sqrt(128)) * log2(e)
  short8 onesf = {16256, 16256, 16256, 16256, 16256, 16256, 16256, 16256};  // bf16 1.0 x8

  for (int phase = 0; phase < 2; phase++) {
    const int qt = phase ? p : 15 - p;   // 128-row q-tile index
    const int rw = qt * 128 + w * 32;    // this wave's first q-row
    const int nkb = 2 * (qt + 1);        // 64-key blocks this tile

    short8 qf[2][4];
#pragma unroll
    for (int qh = 0; qh < 2; qh++)
#pragma unroll
      for (int ks = 0; ks < 4; ks++)
        qf[qh][ks] = *(const short8*)(qkv + (rowbase + rw + qh * 16 + l16) * NQKV + h * 128 + ks * 32 + quad * 8);

    floatx4 acc[2][8] = {};
    floatx4 accl[2] = {};

    __syncthreads();  // protect buf0 from previous phase's reads
    // prologue DMA: kb=0 -> buffer 0
    {
      const u16* Kg = Kg0;
      const u16* Vg = Vg0;
#pragma unroll
      for (int ii = 0; ii < 4; ii++) {
        int p7 = (quad + 4 * ii) & 7;
        int grow = grow0 + 8 * ii;
        gl2lds16(Kg + (size_t)grow * NQKV + ((kslot ^ p7) * 8),
                 &Kl[0][0] + w * 2048 + ii * 512 + lane * 8);
      }
#pragma unroll
      for (int ii = 0; ii < 4; ii++) {
        int d = vd0 + ii * 8;
        gl2lds16(Vg + (size_t)d * 2048 + ((vslot ^ (d & 7)) * 8),
                 &Vl[0][0] + w * 2048 + ii * 512 + lane * 8);
      }
    }

    for (int kb = 0; kb < nkb; kb++) {
      const int cur = kb & 1;
      __syncthreads();  // drains DMA for buf[cur]; releases buf[cur^1] reads
      if (kb + 1 < nkb) {  // prefetch kb+1 into the other buffer
        const u16* Kg = Kg0 + (size_t)(kb + 1) * 64 * NQKV;
        const u16* Vg = Vg0 + (kb + 1) * 64;
        u16* KlN = &Kl[cur ^ 1][0];
        u16* VlN = &Vl[cur ^ 1][0];
#pragma unroll
        for (int ii = 0; ii < 4; ii++) {
          int p7 = (quad + 4 * ii) & 7;
          int grow = grow0 + 8 * ii;
          gl2lds16(Kg + (size_t)grow * NQKV + ((kslot ^ p7) * 8),
                   KlN + w * 2048 + ii * 512 + lane * 8);
        }
#pragma unroll
        for (int ii = 0; ii < 4; ii++) {
          int d = vd0 + ii * 8;
          gl2lds16(Vg + (size_t)d * 2048 + ((vslot ^ (d & 7)) * 8),
                   VlN + w * 2048 + ii * 512 + lane * 8);
        }
      }
      // wave-uniform skip: this wave's rows end at rw+31; block keys start kb*64
      if (kb * 64 > rw + 31) continue;  // barriers already done; DMA issued
      const u16* KlB = &Kl[cur][0];
      const u16* VlB = &Vl[cur][0];

      // ---- QK^T (swapped: A=K, B=Q[qh]) ----
      floatx4 sc[2][4];
#pragma unroll
      for (int nt = 0; nt < 4; nt++) {
        const u16* Krow = KlB + (nt * 16 + l16) * 128;
        short8 kf[4];
#pragma unroll
        for (int ks = 0; ks < 4; ks++)
          kf[ks] = *(const short8*)(Krow + (((ks * 4 + quad) ^ sx) * 8));
#pragma unroll
        for (int qh = 0; qh < 2; qh++) {
          floatx4 s = {0.f, 0.f, 0.f, 0.f};
#pragma unroll
          for (int ks = 0; ks < 4; ks++) s = __builtin_amdgcn_mfma_f32_16x16x32_bf16(kf[ks], qf[qh][ks], s, 0, 0, 0);
          sc[qh][nt] = s;
        }
      }
      // ---- P = exp2(score*c2), causal mask, trunc-pack into A-frags ----
      const bool diag = (kb * 64 + 63) > rw;
      short8 pfr[2][2];
#pragma unroll
      for (int qh = 0; qh < 2; qh++) {
        const int qrow = rw + qh * 16 + l16;
        uint32_t pw[8];
#pragma unroll
        for (int nt = 0; nt < 4; nt++) {
          uint32_t w0 = 0, w1 = 0;
#pragma unroll
          for (int r = 0; r < 4; r++) {
            float e = EXP2F(sc[qh][nt][r] * c2);
            if (diag) {
              int keyg = kb * 64 + quad * 8 + (nt & 1) * 4 + (nt >> 1) * 32 + r;
              if (keyg > qrow) e = 0.f;
            }
            uint32_t b = __float_as_uint(e) >> 16;
            if (r == 0) w0 = b;
            else if (r == 1) w0 |= b << 16;
            else if (r == 2) w1 = b;
            else w1 |= b << 16;
          }
          pw[nt * 2] = w0;
          pw[nt * 2 + 1] = w1;
        }
        union { short8 v; uint32_t u[4]; } pu0, pu1;
        pu0.u[0] = pw[0]; pu0.u[1] = pw[1]; pu0.u[2] = pw[2]; pu0.u[3] = pw[3];
        pu1.u[0] = pw[4]; pu1.u[1] = pw[5]; pu1.u[2] = pw[6]; pu1.u[3] = pw[7];
        pfr[qh][0] = pu0.v; pfr[qh][1] = pu1.v;
        accl[qh] = __builtin_amdgcn_mfma_f32_16x16x32_bf16(pfr[qh][0], onesf, accl[qh], 0, 0, 0);
        accl[qh] = __builtin_amdgcn_mfma_f32_16x16x32_bf16(pfr[qh][1], onesf, accl[qh], 0, 0, 0);
      }
      // ---- PV: each V fragment read feeds both qh ----
#pragma unroll
      for (int nto = 0; nto < 8; nto++) {
        const u16* Vrow = VlB + (nto * 16 + l16) * 64;
        short8 vf0 = *(const short8*)(Vrow + ((quad ^ sx) * 8));
        short8 vf1 = *(const short8*)(Vrow + (((quad + 4) ^ sx) * 8));
#pragma unroll
        for (int qh = 0; qh < 2; qh++) {
          acc[qh][nto] = __builtin_amdgcn_mfma_f32_16x16x32_bf16(pfr[qh][0], vf0, acc[qh][nto], 0, 0, 0);
          acc[qh][nto] = __builtin_amdgcn_mfma_f32_16x16x32_bf16(pfr[qh][1], vf1, acc[qh][nto], 0, 0, 0);
        }
      }
    }
    // ---- epilogue for this q-tile ----
#pragma unroll
    for (int qh = 0; qh < 2; qh++)
#pragma unroll
      for (int r = 0; r < 4; r++) {
        float inv = 1.0f / accl[qh][r];
        int rowg = rw + qh * 16 + quad * 4 + r;
#pragma unroll
        for (int nto = 0; nto < 8; nto++) {
          int col = h * 128 + nto * 16 + l16;
          ctx[(rowbase + rowg) * 2048 + col] = f2bf(acc[qh][nto][r] * inv);
        }
      }
  }
}

extern "C" void kernel_launch(void* const* d_in, const int* in_sizes, int n_in,
                              void* d_out, int out_size, void* d_ws, size_t ws_size,
                              hipStream_t stream) {
  const float* x  = (const float*)d_in[0];
  const int* pos  = (const int*)d_in[1];
  const float* Wq = (const float*)d_in[2];
  const float* Wk = (const float*)d_in[3];
  const float* Wv = (const float*)d_in[4];
  const float* Wo = (const float*)d_in[5];
  float* out = (float*)d_out;
  char* ws = (char*)d_ws;
  // ws layout (bf16): Xb[4096][2048] | WT[3072][2048] | WoT[2048][2048] | QKV[4096][3072] | CTX[4096][2048]
  u16* Xb  = (u16*)(ws);
  u16* WT  = (u16*)(ws + 16777216);
  u16* WoT = (u16*)(ws + 29360128);
  u16* QKV = (u16*)(ws + 37748736);
  u16* CTX = (u16*)(ws + 62914560);
  u16* VT  = Xb;  // [B*NKV][128][2048] bf16, 4 MB, reuses Xb after gemm1

  hipLaunchKernelGGL(cast_k, dim3(8192), dim3(256), 0, stream, x, Xb, 2097152);

  dim3 tb(32, 8);
  hipLaunchKernelGGL(wtrans_k, dim3(64, 64, 4), tb, 0, stream, Wq, Wk, Wv, Wo, WT, WoT);

  // QKV projection: 4096x3072x2048, 256^2 8-phase (R4 version), grid 192 (192%8==0)
  hipLaunchKernelGGL(gemm256_k, dim3(192), dim3(512), 0, stream, Xb, WT, QKV, 3072, 2048);
  hipLaunchKernelGGL(rope_k, dim3(20480), dim3(256), 0, stream, QKV, pos);
  hipLaunchKernelGGL(vtrans_k, dim3(64, 4, 8), tb, 0, stream, QKV, VT);
  hipLaunchKernelGGL(attn_k, dim3(8, 16, 2), dim3(256), 0, stream, QKV, VT, CTX);
  hipLaunchKernelGGL(HIP_KERNEL_NAME(gemm_bt<true>), dim3(16, 32), dim3(256), 0, stream,
                     CTX, WoT, (void*)out, 4096, 2048, 2048);
}

// Round 7
// 296.358 us; speedup vs baseline: 1.0960x; 1.0960x over previous
//
#include <hip/hip_runtime.h>
#include <stdint.h>

typedef unsigned short u16;
typedef __attribute__((ext_vector_type(8))) short short8;
typedef __attribute__((ext_vector_type(4))) float floatx4;

#define S_LEN 2048
#define NQKV 3072

#if __has_builtin(__builtin_amdgcn_exp2f)
#define EXP2F __builtin_amdgcn_exp2f
#else
#define EXP2F exp2f
#endif

__device__ inline float bf2f(u16 u) {
  union { uint32_t u; float f; } v; v.u = ((uint32_t)u) << 16; return v.f;
}
__device__ inline u16 f2bf(float f) {
  union { float f; uint32_t u; } v; v.f = f;
  uint32_t r = v.u + 0x7fffu + ((v.u >> 16) & 1u);
  return (u16)(r >> 16);
}
__device__ inline void gl2lds16(const u16* g, u16* l) {
  __builtin_amdgcn_global_load_lds((const __attribute__((address_space(1))) uint32_t*)g,
                                   (__attribute__((address_space(3))) uint32_t*)l, 16, 0, 0);
}

// ---------------- fused prep: x cast (blocks 0..8191) + 4 weight transposes ----------------
// cast: fp32 x -> bf16 Xb, 4 elems/thread.
// wtrans: fp32 [2048][N] -> bf16 [N][2048] via 32x33 LDS tile.
__global__ void prep_k(const float* __restrict__ x, u16* __restrict__ Xb,
                       const float* __restrict__ Wq, const float* __restrict__ Wk,
                       const float* __restrict__ Wv, const float* __restrict__ Wo,
                       u16* __restrict__ WT, u16* __restrict__ WoT) {
  __shared__ u16 tile[32][33];
  const int b = blockIdx.x, t = threadIdx.x;
  if (b < 8192) {  // cast
    int i = b * 256 + t;
    float4 v = ((const float4*)x)[i];
    ushort4 o;
    o.x = f2bf(v.x); o.y = f2bf(v.y); o.z = f2bf(v.z); o.w = f2bf(v.w);
    ((ushort4*)Xb)[i] = o;
    return;
  }
  int wb = b - 8192;
  const float* src; u16* dst; int bx, by;
  if (wb < 4096)      { src = Wq; dst = WT;                       bx = wb & 63;  by = wb >> 6; }
  else if (wb < 5120) { src = Wk; dst = WT + (size_t)2048 * 2048; bx = (wb - 4096) & 15; by = (wb - 4096) >> 4; }
  else if (wb < 6144) { src = Wv; dst = WT + (size_t)2560 * 2048; bx = (wb - 5120) & 15; by = (wb - 5120) >> 4; }
  else                { src = Wo; dst = WoT;                      bx = (wb - 6144) & 63; by = (wb - 6144) >> 6; }
  const int N = (wb >= 4096 && wb < 6144) ? 512 : 2048;
  int n0 = bx * 32, k0 = by * 32;
  int tx = t & 31, ty = t >> 5;  // 32 x 8
#pragma unroll
  for (int i = 0; i < 4; i++)
    tile[ty + 8 * i][tx] = f2bf(src[(size_t)(k0 + ty + 8 * i) * N + n0 + tx]);
  __syncthreads();
#pragma unroll
  for (int i = 0; i < 4; i++)
    dst[(size_t)(n0 + ty + 8 * i) * 2048 + k0 + tx] = tile[tx][ty + 8 * i];
}

// ---------------- V transpose: qkv V region [key][d] -> vt [bz][d][key] (bf16) ----------------
__global__ void vtrans_k(const u16* __restrict__ qkv, u16* __restrict__ vt) {
  __shared__ u16 tile[32][33];
  int bk = blockIdx.x * 32, bd = blockIdx.y * 32, bz = blockIdx.z;
  int bb = bz >> 2, kvh = bz & 3;
  const u16* src = qkv + ((size_t)bb * S_LEN) * NQKV + 2560 + kvh * 128;
  u16* dst = vt + (size_t)bz * 128 * 2048;
  int tx = threadIdx.x, ty = threadIdx.y;
#pragma unroll
  for (int i = 0; i < 4; i++)
    tile[ty + 8 * i][tx] = src[(size_t)(bk + ty + 8 * i) * NQKV + bd + tx];
  __syncthreads();
#pragma unroll
  for (int i = 0; i < 4; i++)
    dst[(size_t)(bd + ty + 8 * i) * 2048 + bk + tx] = tile[tx][ty + 8 * i];
}

// ---------------- GEMM (legacy 128x128, used for Wo projection) ----------------
template <bool OUTF32>
__global__ __launch_bounds__(256) void gemm_bt(const u16* __restrict__ A, const u16* __restrict__ Bt,
                                               void* __restrict__ Cv, int M, int N, int K) {
  __shared__ u16 As[128 * 32];
  __shared__ u16 Bs[128 * 32];
  const int m0 = blockIdx.y * 128, n0 = blockIdx.x * 128;
  const int t = threadIdx.x, w = t >> 6, lane = t & 63;
  const int quad = lane >> 4, l16 = lane & 15;
  const int wm = (w >> 1) * 64, wn = (w & 1) * 64;
  const int lrow = lane >> 2, lk = (lane & 3) * 8;
  floatx4 acc[4][4] = {};
  for (int k0 = 0; k0 < K; k0 += 32) {
#pragma unroll
    for (int c = 2 * w; c <= 2 * w + 1; ++c) {
      int row = c * 16 + lrow;
      gl2lds16(A + (size_t)(m0 + row) * K + k0 + lk, As + c * 512 + lane * 8);
      gl2lds16(Bt + (size_t)(n0 + row) * K + k0 + lk, Bs + c * 512 + lane * 8);
    }
    __syncthreads();
    short8 a[4], b[4];
#pragma unroll
    for (int mt = 0; mt < 4; mt++) a[mt] = *(const short8*)(As + (wm + mt * 16 + l16) * 32 + quad * 8);
#pragma unroll
    for (int nt = 0; nt < 4; nt++) b[nt] = *(const short8*)(Bs + (wn + nt * 16 + l16) * 32 + quad * 8);
#pragma unroll
    for (int mt = 0; mt < 4; mt++)
#pragma unroll
      for (int nt = 0; nt < 4; nt++)
        acc[mt][nt] = __builtin_amdgcn_mfma_f32_16x16x32_bf16(a[mt], b[nt], acc[mt][nt], 0, 0, 0);
    __syncthreads();
  }
#pragma unroll
  for (int mt = 0; mt < 4; mt++)
#pragma unroll
    for (int nt = 0; nt < 4; nt++)
#pragma unroll
      for (int r = 0; r < 4; r++) {
        int row = m0 + wm + mt * 16 + quad * 4 + r;
        int col = n0 + wn + nt * 16 + l16;
        if (OUTF32)
          ((float*)Cv)[(size_t)row * N + col] = acc[mt][nt][r];
        else
          ((u16*)Cv)[(size_t)row * N + col] = f2bf(acc[mt][nt][r]);
      }
}

// ---------------- GEMM 256x256 8-phase (R4 structure) + fused RoPE epilogue ----------------
// R4-verified K-loop (66.6us): fragment reuse across quadrant phases (24
// ds_read_b128/wave/K-tile = geometry min), slot-XOR swizzle, counted vmcnt.
// R7 additions:
//  - B-column remap: rb = wn*16 + nt*64 + l16 (was wn*32+nt*16+l16). Pure
//    relabeling of which wave/acc-slot computes which column (same dot
//    products, same k-order -> pre-rope values bit-identical). rb&7 = l16&7
//    unchanged -> same bank-conflict-free property. Now acc[..][nt=0/1][r]
//    hold the RoPE pair (d, d+64) in-register.
//  - RoPE fused into the epilogue for Q/K tiles (n0 < 2560; V tiles n0>=2560
//    written unrotated). Applied to the UNROUNDED f32 accumulator (one fewer
//    bf16 round-trip than the separate rope_k -> closer to f32 reference).
//    rope_k kernel + its 21MB RW pass eliminated.
__global__ __launch_bounds__(512, 2) void gemm256_k(const u16* __restrict__ A,
                                                    const u16* __restrict__ Bt,
                                                    u16* __restrict__ C,
                                                    const int* __restrict__ pos,
                                                    int N, int K) {
  __shared__ u16 Al[2][2][8192];
  __shared__ u16 Bl[2][2][8192];
  const int TN = N >> 8;
  int flat = blockIdx.x;
  const int cpx = gridDim.x >> 3;  // grid % 8 == 0 guaranteed by launch config
  flat = (flat & 7) * cpx + (flat >> 3);
  const int m0 = (flat / TN) << 8, n0 = (flat % TN) << 8;
  const int t = threadIdx.x, w = t >> 6, lane = t & 63;
  const int quad = lane >> 4, l16 = lane & 15;
  const int wm = w >> 2, wn = w & 3;
  const int sr = t >> 3, sl = t & 7;  // staging: row-in-round, lds slot
  floatx4 acc[2][2][4][2] = {};
  const int NKT = K >> 6;

  const int ra_l = wm * 64 + l16;  // + mt*16 ; A row within 128-half
  const int rb_l = wn * 16 + l16;  // + nt*64 ; B row within 128-half (RoPE-pair remap)

  // prologue: stage kt0 into buf0 (A0,B0,B1,A1), full drain once
#pragma unroll
  for (int round = 0; round < 2; round++) {
    int r = round * 64 + sr;
    int so = (sl ^ (r & 7)) << 3;
    gl2lds16(A + (size_t)(m0 + r) * K + so, &Al[0][0][0] + round * 4096 + t * 8);
    gl2lds16(Bt + (size_t)(n0 + r) * K + so, &Bl[0][0][0] + round * 4096 + t * 8);
    gl2lds16(Bt + (size_t)(n0 + 128 + r) * K + so, &Bl[0][1][0] + round * 4096 + t * 8);
    gl2lds16(A + (size_t)(m0 + 128 + r) * K + so, &Al[0][1][0] + round * 4096 + t * 8);
  }
  asm volatile("s_waitcnt vmcnt(0)" ::: "memory");
  __builtin_amdgcn_s_barrier();

  short8 af[4][2];     // current A-half fragments (reused by 2 phases)
  short8 bf[2][2][2];  // [nh][nt][ks] both B-half fragments

  for (int kt = 0; kt < NKT; kt++) {
    const int c = kt & 1;
    const u16* Ab = &Al[c][0][0];
    const u16* Bb = &Bl[c][0][0];
    u16* An = &Al[c ^ 1][0][0];
    u16* Bn = &Bl[c ^ 1][0][0];
    const int k1 = (kt + 1) << 6;
    const bool pf = (kt + 1 < NKT);
#pragma unroll
    for (int ph = 0; ph < 4; ph++) {
      // quadrant sequence: (mh,nh) = (0,0),(0,1),(1,1),(1,0)
      const int mh = (ph >> 1);
      const int nh = (ph == 1 || ph == 2) ? 1 : 0;
      // ---- ds-read ONLY the new fragments for this phase ----
      if (ph == 0 || ph == 2) {  // new A-half
#pragma unroll
        for (int mt = 0; mt < 4; mt++) {
          int ra = ra_l + mt * 16;
          const u16* base = Ab + mh * 8192 + ra * 64;
#pragma unroll
          for (int ks = 0; ks < 2; ks++)
            af[mt][ks] = *(const short8*)(base + (((ks * 4 + quad) ^ (ra & 7)) << 3));
        }
      }
      if (ph == 0 || ph == 1) {  // new B-half
#pragma unroll
        for (int nt = 0; nt < 2; nt++) {
          int rb = rb_l + nt * 64;
          const u16* base = Bb + nh * 8192 + rb * 64;
#pragma unroll
          for (int ks = 0; ks < 2; ks++)
            bf[nh][nt][ks] = *(const short8*)(base + (((ks * 4 + quad) ^ (rb & 7)) << 3));
        }
      }
      // ---- stage one half-tile of kt+1 (order A0,B0,B1,A1) ----
      if (pf) {
        const u16* G;
        u16* L;
        int rbase;
        if (ph == 0)      { G = A;  L = An;        rbase = m0; }
        else if (ph == 1) { G = Bt; L = Bn;        rbase = n0; }
        else if (ph == 2) { G = Bt; L = Bn + 8192; rbase = n0 + 128; }
        else              { G = A;  L = An + 8192; rbase = m0 + 128; }
#pragma unroll
        for (int round = 0; round < 2; round++) {
          int r = round * 64 + sr;
          gl2lds16(G + (size_t)(rbase + r) * K + k1 + ((sl ^ (r & 7)) << 3),
                   L + round * 4096 + t * 8);
        }
      }
      __builtin_amdgcn_s_barrier();
      asm volatile("s_waitcnt lgkmcnt(0)" ::: "memory");
      __builtin_amdgcn_s_setprio(1);
#pragma unroll
      for (int mt = 0; mt < 4; mt++)
#pragma unroll
        for (int nt = 0; nt < 2; nt++)
#pragma unroll
          for (int ks = 0; ks < 2; ks++)
            acc[mh][nh][mt][nt] =
                __builtin_amdgcn_mfma_f32_16x16x32_bf16(af[mt][ks], bf[nh][nt][ks], acc[mh][nh][mt][nt], 0, 0, 0);
      __builtin_amdgcn_s_setprio(0);
      if (ph != 2) asm volatile("s_waitcnt vmcnt(4)" ::: "memory");
      __builtin_amdgcn_s_barrier();
    }
  }
  // ---- epilogue: RoPE (Q/K tiles) + bf16 write ----
  const bool dorope = (n0 < 2560);
  const float rfreq = __expf(-(float)(wn * 16 + l16) * 0.015625f * 9.210340371976184f);
#pragma unroll
  for (int mh = 0; mh < 2; mh++)
#pragma unroll
    for (int mt = 0; mt < 4; mt++)
#pragma unroll
      for (int r = 0; r < 4; r++) {
        int row = m0 + mh * 128 + wm * 64 + mt * 16 + quad * 4 + r;
        float cc = 1.f, sn = 0.f;
        if (dorope) {
          float ang = (float)pos[row & (S_LEN - 1)] * rfreq;
          cc = cosf(ang); sn = sinf(ang);
        }
#pragma unroll
        for (int nh = 0; nh < 2; nh++) {
          float a0 = acc[mh][nh][mt][0][r], a1 = acc[mh][nh][mt][1][r];
          float o0 = dorope ? (a0 * cc - a1 * sn) : a0;
          float o1 = dorope ? (a1 * cc + a0 * sn) : a1;
          int colb = n0 + nh * 128 + wn * 16 + l16;
          C[(size_t)row * N + colb]      = f2bf(o0);
          C[(size_t)row * N + colb + 64] = f2bf(o1);
        }
      }
}

// ---------------- Flash attention, causal GQA (REVERTED to R4: 16 q/wave) ----------------
// R6 (32 q/wave, 256 blocks) regressed 62->86us: 1 wave/SIMD exposed all DMA
// and LDS latency (Occupancy 10%). This is the verified R4 version: 512
// blocks = 2 waves/SIMD, swapped QK^T + kperm staging, P entirely in-register,
// XOR swizzles, DMA double-buffer, one barrier/iter, no max-tracking.
__global__ __launch_bounds__(256) void attn_k(const u16* __restrict__ qkv,
                                              const u16* __restrict__ vt,
                                              u16* __restrict__ ctx) {
  __shared__ u16 Kl[2][64 * 128];      // 2 x 16384 B, [pos][d] swizzled, rows kperm'd
  __shared__ u16 Vl[2][128 * 64];      // 2 x 16384 B, [d][key] swizzled
  const int p = blockIdx.x;
  const int h = blockIdx.y, bb = blockIdx.z;
  const int kvh = h >> 2;
  const int t = threadIdx.x, w = t >> 6, lane = t & 63;
  const int quad = lane >> 4, l16 = lane & 15;
  const int sx = l16 & 7;              // read-side swizzle key
  const int kslot = lane & 15;
  const int vd0 = w * 32 + (lane >> 3);
  const int vslot = lane & 7;
  const int grow0 = (w & 1) * 4 + (w >> 1) * 32 + quad;
  const size_t rowbase = (size_t)bb * S_LEN;
  const u16* Kg0 = qkv + rowbase * NQKV + 2048 + kvh * 128;
  const u16* Vg0 = vt + (size_t)(bb * 4 + kvh) * 128 * 2048;
  const float c2 = 0.12751744f;  // (1/sqrt(128)) * log2(e)
  short8 onesf = {16256, 16256, 16256, 16256, 16256, 16256, 16256, 16256};  // bf16 1.0 x8

  for (int phase = 0; phase < 2; phase++) {
    const int qt = phase ? p : 31 - p;  // q-tile index; qt+1 k-iters
    const int rw = qt * 64 + w * 16;    // this wave's first q-row
    const int qrow = rw + l16;          // this lane's q-row (swapped layout: col=q)

    short8 qf[4];
#pragma unroll
    for (int ks = 0; ks < 4; ks++)
      qf[ks] = *(const short8*)(qkv + (rowbase + rw + l16) * NQKV + h * 128 + ks * 32 + quad * 8);

    floatx4 acc[8] = {};
    floatx4 accl = {0.f, 0.f, 0.f, 0.f};

    __syncthreads();  // protect buf0 from previous phase's reads
    // prologue DMA: kb=0 -> buffer 0
    {
      const u16* Kg = Kg0;
      const u16* Vg = Vg0;
#pragma unroll
      for (int ii = 0; ii < 4; ii++) {
        int p7 = (quad + 4 * ii) & 7;  // (position)&7 for the slot swizzle
        int grow = grow0 + 8 * ii;     // permuted global key row
        gl2lds16(Kg + (size_t)grow * NQKV + ((kslot ^ p7) * 8),
                 &Kl[0][0] + w * 2048 + ii * 512 + lane * 8);
      }
#pragma unroll
      for (int ii = 0; ii < 4; ii++) {
        int d = vd0 + ii * 8;
        gl2lds16(Vg + (size_t)d * 2048 + ((vslot ^ (d & 7)) * 8),
                 &Vl[0][0] + w * 2048 + ii * 512 + lane * 8);
      }
    }

    for (int kb = 0; kb <= qt; kb++) {
      const int cur = kb & 1;
      __syncthreads();  // drains DMA for buf[cur]; releases buf[cur^1] reads
      if (kb < qt) {    // prefetch kb+1 into the other buffer, overlapping compute
        const u16* Kg = Kg0 + (size_t)(kb + 1) * 64 * NQKV;
        const u16* Vg = Vg0 + (kb + 1) * 64;
        u16* KlN = &Kl[cur ^ 1][0];
        u16* VlN = &Vl[cur ^ 1][0];
#pragma unroll
        for (int ii = 0; ii < 4; ii++) {
          int p7 = (quad + 4 * ii) & 7;
          int grow = grow0 + 8 * ii;
          gl2lds16(Kg + (size_t)grow * NQKV + ((kslot ^ p7) * 8),
                   KlN + w * 2048 + ii * 512 + lane * 8);
        }
#pragma unroll
        for (int ii = 0; ii < 4; ii++) {
          int d = vd0 + ii * 8;
          gl2lds16(Vg + (size_t)d * 2048 + ((vslot ^ (d & 7)) * 8),
                   VlN + w * 2048 + ii * 512 + lane * 8);
        }
      }
      const u16* KlB = &Kl[cur][0];
      const u16* VlB = &Vl[cur][0];

      // ---- QK^T (swapped: A=K, B=Q -> lane holds S[pos=quad*4+r][q=l16]) ----
      floatx4 sc[4];
#pragma unroll
      for (int nt = 0; nt < 4; nt++) {
        const u16* Krow = KlB + (nt * 16 + l16) * 128;
        short8 kf[4];
#pragma unroll
        for (int ks = 0; ks < 4; ks++)
          kf[ks] = *(const short8*)(Krow + (((ks * 4 + quad) ^ sx) * 8));
        floatx4 s = {0.f, 0.f, 0.f, 0.f};
#pragma unroll
        for (int ks = 0; ks < 4; ks++) s = __builtin_amdgcn_mfma_f32_16x16x32_bf16(kf[ks], qf[ks], s, 0, 0, 0);
        sc[nt] = s;
      }
      // ---- P = exp2(score*c2), causal mask, trunc-pack DIRECTLY into A-frags ----
      const bool diag = (kb == qt);
      uint32_t pw[8];
#pragma unroll
      for (int nt = 0; nt < 4; nt++) {
        uint32_t w0 = 0, w1 = 0;
#pragma unroll
        for (int r = 0; r < 4; r++) {
          float e = EXP2F(sc[nt][r] * c2);
          if (diag) {
            int keyg = kb * 64 + quad * 8 + (nt & 1) * 4 + (nt >> 1) * 32 + r;
            if (keyg > qrow) e = 0.f;
          }
          uint32_t b = __float_as_uint(e) >> 16;
          if (r == 0) w0 = b;
          else if (r == 1) w0 |= b << 16;
          else if (r == 2) w1 = b;
          else w1 |= b << 16;
        }
        pw[nt * 2] = w0;
        pw[nt * 2 + 1] = w1;
      }
      union { short8 v; uint32_t u[4]; } pu0, pu1;
      pu0.u[0] = pw[0]; pu0.u[1] = pw[1]; pu0.u[2] = pw[2]; pu0.u[3] = pw[3];
      pu1.u[0] = pw[4]; pu1.u[1] = pw[5]; pu1.u[2] = pw[6]; pu1.u[3] = pw[7];
      const short8 pf0 = pu0.v, pf1 = pu1.v;  // PV A-frags, keys 0-31 / 32-63

      // ---- PV (+ ones-column row-sum into accl) ----
      accl = __builtin_amdgcn_mfma_f32_16x16x32_bf16(pf0, onesf, accl, 0, 0, 0);
      accl = __builtin_amdgcn_mfma_f32_16x16x32_bf16(pf1, onesf, accl, 0, 0, 0);
#pragma unroll
      for (int nto = 0; nto < 8; nto++) {
        const u16* Vrow = VlB + (nto * 16 + l16) * 64;
        short8 vf0 = *(const short8*)(Vrow + ((quad ^ sx) * 8));
        short8 vf1 = *(const short8*)(Vrow + (((quad + 4) ^ sx) * 8));
        acc[nto] = __builtin_amdgcn_mfma_f32_16x16x32_bf16(pf0, vf0, acc[nto], 0, 0, 0);
        acc[nto] = __builtin_amdgcn_mfma_f32_16x16x32_bf16(pf1, vf1, acc[nto], 0, 0, 0);
      }
    }
    // ---- epilogue for this q-tile (lane holds O[q=quad*4+r][d=l16]) ----
#pragma unroll
    for (int r = 0; r < 4; r++) {
      float inv = 1.0f / accl[r];
      int rowg = rw + quad * 4 + r;
#pragma unroll
      for (int nto = 0; nto < 8; nto++) {
        int col = h * 128 + nto * 16 + l16;
        ctx[(rowbase + rowg) * 2048 + col] = f2bf(acc[nto][r] * inv);
      }
    }
  }
}

extern "C" void kernel_launch(void* const* d_in, const int* in_sizes, int n_in,
                              void* d_out, int out_size, void* d_ws, size_t ws_size,
                              hipStream_t stream) {
  const float* x  = (const float*)d_in[0];
  const int* pos  = (const int*)d_in[1];
  const float* Wq = (const float*)d_in[2];
  const float* Wk = (const float*)d_in[3];
  const float* Wv = (const float*)d_in[4];
  const float* Wo = (const float*)d_in[5];
  float* out = (float*)d_out;
  char* ws = (char*)d_ws;
  // ws layout (bf16): Xb[4096][2048] | WT[3072][2048] | WoT[2048][2048] | QKV[4096][3072] | CTX[4096][2048]
  u16* Xb  = (u16*)(ws);
  u16* WT  = (u16*)(ws + 16777216);
  u16* WoT = (u16*)(ws + 29360128);
  u16* QKV = (u16*)(ws + 37748736);
  u16* CTX = (u16*)(ws + 62914560);
  u16* VT  = Xb;  // [B*NKV][128][2048] bf16, 4 MB, reuses Xb after gemm1

  // prep: 8192 cast blocks + 10240 transpose blocks
  hipLaunchKernelGGL(prep_k, dim3(18432), dim3(256), 0, stream, x, Xb, Wq, Wk, Wv, Wo, WT, WoT);

  // QKV projection + fused RoPE: 4096x3072x2048, grid 192 (192%8==0)
  hipLaunchKernelGGL(gemm256_k, dim3(192), dim3(512), 0, stream, Xb, WT, QKV, pos, 3072, 2048);
  dim3 tb(32, 8);
  hipLaunchKernelGGL(vtrans_k, dim3(64, 4, 8), tb, 0, stream, QKV, VT);
  hipLaunchKernelGGL(attn_k, dim3(16, 16, 2), dim3(256), 0, stream, QKV, VT, CTX);
  hipLaunchKernelGGL(HIP_KERNEL_NAME(gemm_bt<true>), dim3(16, 32), dim3(256), 0, stream,
                     CTX, WoT, (void*)out, 4096, 2048, 2048);
}